// Round 1
// baseline (8151.487 us; speedup 1.0000x reference)
//
#include <hip/hip_runtime.h>
#include <math.h>

// Problem constants
#define KK     128     // pointer key dim
#define HH     384     // hidden = K*NP
#define H3     1152    // 3*H
#define PP     200     // program dim
#define LL     50      // scratch length
#define VV     512     // value vocab
#define BB     256     // batch
#define II     16      // instruction words
#define NSTEPS 3

#define VP     513     // vals LDS pitch (pad +1: avoids 64-way bank conflict in output phase)
#define KP     129     // keys LDS pitch (pad +1: avoids conflict in logits dots)

#define NT     512     // threads per block (8 waves)

struct Smem {
    float vals[LL * VP];   // 25650
    float keys[LL * KP];   // 6450
    float h[HH];           // 384
    float gi[H3];          // 1152
    float gh[H3];          // 1152
    float prog[PP];        // 200
    float ra[LL];          // 50
    float wmm[LL];         // 50
    float rl[LL];          // 50
    float wl[LL];          // 50
    float rowoff[LL];      // 50  (max + log(sumexp) per row)
};                         // total ~141 KB (< 160 KB LDS/CU, gfx950)

__global__ __launch_bounds__(NT, 1)
void symop_main(const int* __restrict__ instr,
                const float* __restrict__ gate_emb,
                const float* __restrict__ program_emb,
                const float* __restrict__ primitive_emb,
                const float* __restrict__ w_ih,
                const float* __restrict__ w_hh,
                const float* __restrict__ b_ih,
                const float* __restrict__ b_hh,
                const float* __restrict__ keys_g,
                const float* __restrict__ init_value,
                float* __restrict__ out)
{
    __shared__ Smem sm;

    const int tid  = threadIdx.x;
    const int lane = tid & 63;
    const int wid  = tid >> 6;
    const int b    = blockIdx.x;

    // --- init: keys -> LDS, h0 = tile(keys[0], 3), vals = init_value ---
    for (int idx = tid; idx < LL * KK; idx += NT) {
        int l = idx >> 7, k = idx & 127;
        sm.keys[l * KP + k] = keys_g[idx];
    }
    for (int j = tid; j < HH; j += NT) sm.h[j] = keys_g[j & 127];
    for (int idx = tid; idx < LL * VV; idx += NT) {
        int l = idx >> 9, v = idx & 511;
        sm.vals[l * VP + v] = init_value[v];
    }
    __syncthreads();

    for (int i = 0; i < II; ++i) {
        const int word = instr[i * BB + b];
        // gate softmax (2 logits, redundant per-thread)
        const float ge0 = gate_emb[2 * word], ge1 = gate_emb[2 * word + 1];
        const float gmx = fmaxf(ge0, ge1);
        const float e0 = expf(ge0 - gmx), e1 = expf(ge1 - gmx);
        const float g0 = e0 / (e0 + e1), g1 = 1.0f - g0;
        const float* prim = primitive_emb + (long)word * VV;
        const float* pge  = program_emb + (long)word * PP;

        for (int k = tid; k < PP; k += NT) sm.prog[k] = pge[k];
        __syncthreads();

        // gi = W_ih @ program + b_ih  (constant over the 3 steps of this word)
        // wave-cooperative GEMV: wave owns j, lanes over k (coalesced), shuffle-reduce
        for (int j = wid; j < H3; j += 8) {
            const float* wr = w_ih + (long)j * PP;
            float acc = 0.f;
            for (int k = lane; k < PP; k += 64) acc += wr[k] * sm.prog[k];
            for (int m = 32; m >= 1; m >>= 1) acc += __shfl_xor(acc, m, 64);
            if (lane == 0) sm.gi[j] = acc + b_ih[j];
        }
        __syncthreads();

        for (int t = 0; t < NSTEPS; ++t) {
            // --- attention logits: 100 dots of length 128 (threads 0..99) ---
            if (tid < 2 * LL) {
                const int l = (tid < LL) ? tid : tid - LL;
                const float* p  = (tid < LL) ? (sm.h + KK) : (sm.h + 2 * KK);
                const float* kr = sm.keys + l * KP;
                float acc = 0.f;
                for (int k = 0; k < KK; ++k) acc += p[k] * kr[k];
                if (tid < LL) sm.rl[l] = acc; else sm.wl[l] = acc;
            }
            __syncthreads();

            // --- softmax over 50 (redundant per-thread; broadcast LDS reads) ---
            float rmax = -1e30f, wmax = -1e30f;
            for (int l = 0; l < LL; ++l) {
                rmax = fmaxf(rmax, sm.rl[l]);
                wmax = fmaxf(wmax, sm.wl[l]);
            }
            float rsum = 0.f, wsum = 0.f;
            for (int l = 0; l < LL; ++l) {
                rsum += expf(sm.rl[l] - rmax);
                wsum += expf(sm.wl[l] - wmax);
            }
            if (tid < LL) sm.ra[tid] = expf(sm.rl[tid] - rmax) / rsum;
            else if (tid >= 64 && tid < 64 + LL) {
                int l = tid - 64;
                sm.wmm[l] = expf(sm.wl[l] - wmax) / wsum;
            }
            __syncthreads();

            // --- read_value, new_value, vals update (thread owns column v=tid) ---
            {
                float rv = 0.f;
                for (int l = 0; l < LL; ++l) rv += sm.ra[l] * sm.vals[l * VP + tid];
                const float nv = g0 * prim[tid] + g1 * rv;
                for (int l = 0; l < LL; ++l) {
                    const float w = sm.wmm[l];
                    float* cell = sm.vals + l * VP + tid;
                    *cell = w * nv + (1.f - w) * (*cell);
                }
            }

            // --- gh = W_hh @ h + b_hh (reads h, untouched above; no barrier needed) ---
            for (int j = wid; j < H3; j += 8) {
                const float* wr = w_hh + (long)j * HH;
                float acc = 0.f;
                for (int k = lane; k < HH; k += 64) acc += wr[k] * sm.h[k];
                for (int m = 32; m >= 1; m >>= 1) acc += __shfl_xor(acc, m, 64);
                if (lane == 0) sm.gh[j] = acc + b_hh[j];
            }
            __syncthreads();

            // --- GRU pointwise: h[j] update (each j reads only its own h[j]) ---
            if (tid < HH) {
                const int j = tid;
                const float r = 1.f / (1.f + expf(-(sm.gi[j] + sm.gh[j])));
                const float z = 1.f / (1.f + expf(-(sm.gi[HH + j] + sm.gh[HH + j])));
                const float n = tanhf(sm.gi[2 * HH + j] + r * sm.gh[2 * HH + j]);
                sm.h[j] = (1.f - z) * n + z * sm.h[j];
            }
            __syncthreads();
        }
    }

    // --- log_softmax over V per row l: rowoff = max + log(sum exp(x-max)) ---
    for (int l = wid; l < LL; l += 8) {
        const float* row = sm.vals + l * VP;
        float m = -1e30f;
        for (int v = lane; v < VV; v += 64) m = fmaxf(m, row[v]);
        for (int mm = 32; mm >= 1; mm >>= 1) m = fmaxf(m, __shfl_xor(m, mm, 64));
        float s = 0.f;
        for (int v = lane; v < VV; v += 64) s += expf(row[v] - m);
        for (int mm = 32; mm >= 1; mm >>= 1) s += __shfl_xor(s, mm, 64);
        if (lane == 0) sm.rowoff[l] = m + logf(s);
    }
    __syncthreads();

    // --- write actions[b, v, l] = vals[l, v] - rowoff[l]; lanes over l (coalesced) ---
    {
        const int vs = tid >> 6;      // 0..7 (wave id)
        const int l  = tid & 63;      // lane -> l
        if (l < LL) {
            const float off = sm.rowoff[l];
            float* ob = out + (long)b * VV * LL + l;
            for (int vb = 0; vb < VV; vb += 8) {
                const int v = vb + vs;
                ob[(long)v * LL] = sm.vals[l * VP + v] - off;
            }
        }
    }
}

// Output 1: true_actions.T  (L,B) int32 -> (B,L) as float
__global__ void ta_copy(const int* __restrict__ ta, float* __restrict__ out2)
{
    int idx = blockIdx.x * 256 + threadIdx.x;
    if (idx < BB * LL) {
        int b2 = idx / LL, l = idx % LL;
        out2[idx] = (float)ta[l * BB + b2];
    }
}

extern "C" void kernel_launch(void* const* d_in, const int* in_sizes, int n_in,
                              void* d_out, int out_size, void* d_ws, size_t ws_size,
                              hipStream_t stream)
{
    const int*   instr        = (const int*)  d_in[0];
    const int*   true_actions = (const int*)  d_in[1];
    const float* gate_emb     = (const float*)d_in[2];
    const float* program_emb  = (const float*)d_in[3];
    const float* primitive_emb= (const float*)d_in[4];
    const float* w_ih         = (const float*)d_in[5];
    const float* w_hh         = (const float*)d_in[6];
    const float* b_ih         = (const float*)d_in[7];
    const float* b_hh         = (const float*)d_in[8];
    const float* scratch_keys = (const float*)d_in[9];
    const float* init_value   = (const float*)d_in[10];

    float* out = (float*)d_out;
    float* out_actions = out;                          // 256*512*50
    float* out_ta      = out + (long)BB * VV * LL;     // 256*50

    symop_main<<<BB, NT, 0, stream>>>(instr, gate_emb, program_emb, primitive_emb,
                                      w_ih, w_hh, b_ih, b_hh,
                                      scratch_keys, init_value, out_actions);

    ta_copy<<<(BB * LL + 255) / 256, 256, 0, stream>>>(true_actions, out_ta);
}

// Round 2
// 807.817 us; speedup vs baseline: 10.0908x; 10.0908x over previous
//
#include <hip/hip_runtime.h>
#include <math.h>

// Problem constants
#define KK     128
#define HH     384
#define H3     1152
#define PP     200
#define LL     50
#define VV     512
#define BB     256
#define II     16
#define NSTEPS 3

#define VP     513     // vals LDS pitch
#define KP     129     // keys LDS pitch
#define NT     576     // 9 waves; 2*NT == H3 exactly

#define WT_HH_ELEMS (HH * H3)   // 442368
#define WT_IH_ELEMS (PP * H3)   // 230400

__device__ __forceinline__ unsigned short f2bf(float f) {
    unsigned u = __float_as_uint(f);
    unsigned r = u + 0x7FFFu + ((u >> 16) & 1u);   // RNE
    return (unsigned short)(r >> 16);
}
__device__ __forceinline__ float bflo(unsigned u) { return __uint_as_float(u << 16); }
__device__ __forceinline__ float bfhi(unsigned u) { return __uint_as_float(u & 0xFFFF0000u); }

// Pre-pass: wT_hh[k][j] = bf16(w_hh[j][k]);  wT_ih[k][j] = bf16(w_ih[j][k])
__global__ void transpose_bf16(const float* __restrict__ w_hh,
                               const float* __restrict__ w_ih,
                               unsigned short* __restrict__ ws)
{
    int idx = blockIdx.x * 256 + threadIdx.x;
    if (idx < WT_HH_ELEMS) {
        int k = idx / H3, j = idx - k * H3;
        ws[idx] = f2bf(w_hh[(long)j * HH + k]);
    } else if (idx < WT_HH_ELEMS + WT_IH_ELEMS) {
        int r = idx - WT_HH_ELEMS;
        int k = r / H3, j = r - k * H3;
        ws[idx] = f2bf(w_ih[(long)j * PP + k]);
    }
}

struct Smem {
    float vals[LL * VP];
    float keys[LL * KP];
    float h[HH];
    float gi[H3];
    float gh[H3];
    float prog[PP];
    float ra[LL];
    float wmm[LL];
    float rl[LL];
    float wl[LL];
    float rowoff[LL];
};  // ~141 KB

__global__ __launch_bounds__(NT, 1)
void symop_main(const int* __restrict__ instr,
                const float* __restrict__ gate_emb,
                const float* __restrict__ program_emb,
                const float* __restrict__ primitive_emb,
                const unsigned* __restrict__ wT_hh,   // [HH][H3/2] uint pairs
                const unsigned* __restrict__ wT_ih,   // [PP][H3/2]
                const float* __restrict__ b_ih,
                const float* __restrict__ b_hh,
                const float* __restrict__ keys_g,
                const float* __restrict__ init_value,
                float* __restrict__ out)
{
    __shared__ Smem sm;

    const int tid  = threadIdx.x;
    const int lane = tid & 63;
    const int wid  = tid >> 6;
    const int b    = blockIdx.x;

    // init
    for (int idx = tid; idx < LL * KK; idx += NT) {
        int l = idx >> 7, k = idx & 127;
        sm.keys[l * KP + k] = keys_g[idx];
    }
    for (int j = tid; j < HH; j += NT) sm.h[j] = keys_g[j & 127];
    for (int idx = tid; idx < LL * VV; idx += NT) {
        int l = idx >> 9, v = idx & 511;
        sm.vals[l * VP + v] = init_value[v];
    }
    __syncthreads();

    const int j0 = 2 * tid;   // each thread owns outputs j0, j0+1 (j0 < 1152)
    const float2 bh2 = *(const float2*)(b_hh + j0);
    const float2 bi2 = *(const float2*)(b_ih + j0);

    for (int i = 0; i < II; ++i) {
        const int word = instr[i * BB + b];
        const float ge0 = gate_emb[2 * word], ge1 = gate_emb[2 * word + 1];
        const float gmx = fmaxf(ge0, ge1);
        const float e0 = expf(ge0 - gmx), e1 = expf(ge1 - gmx);
        const float g0 = e0 / (e0 + e1), g1 = 1.0f - g0;
        const float* prim = primitive_emb + (long)word * VV;
        const float* pge  = program_emb + (long)word * PP;

        for (int k = tid; k < PP; k += NT) sm.prog[k] = pge[k];
        __syncthreads();

        // gi = W_ih @ prog + b_ih  (thread-per-2-outputs, coalesced bf16 pairs)
        {
            float a0 = 0.f, a1 = 0.f;
            const unsigned* wp = wT_ih + tid;
            #pragma unroll 8
            for (int k = 0; k < PP; ++k) {
                unsigned u = wp[k * (H3 / 2)];
                float pk = sm.prog[k];
                a0 = fmaf(bflo(u), pk, a0);
                a1 = fmaf(bfhi(u), pk, a1);
            }
            sm.gi[j0]     = a0 + bi2.x;
            sm.gi[j0 + 1] = a1 + bi2.y;
        }
        // no barrier needed yet: gi is consumed only after later barriers

        for (int t = 0; t < NSTEPS; ++t) {
            // attention logits: 100 dots of len 128; 4 lanes per dot
            if (tid < 4 * 2 * LL) {
                const int dot = tid >> 2;            // 0..99
                const int sub = tid & 3;
                const int l   = (dot < LL) ? dot : dot - LL;
                const float* p  = (dot < LL) ? (sm.h + KK) : (sm.h + 2 * KK);
                const float* kr = sm.keys + l * KP;
                float acc = 0.f;
                #pragma unroll
                for (int kk = 0; kk < KK / 4; ++kk) {
                    int k = sub + 4 * kk;
                    acc = fmaf(p[k], kr[k], acc);
                }
                acc += __shfl_xor(acc, 1, 64);
                acc += __shfl_xor(acc, 2, 64);
                if (sub == 0) {
                    if (dot < LL) sm.rl[l] = acc; else sm.wl[l] = acc;
                }
            }
            __syncthreads();

            // wave-level softmax over 50: wave0 -> read attn, wave1 -> write mask
            if (wid < 2) {
                const float* src = (wid == 0) ? sm.rl : sm.wl;
                float v = (lane < LL) ? src[lane] : -1e30f;
                float m = v;
                #pragma unroll
                for (int mm = 32; mm >= 1; mm >>= 1) m = fmaxf(m, __shfl_xor(m, mm, 64));
                float e = (lane < LL) ? expf(v - m) : 0.f;
                float s = e;
                #pragma unroll
                for (int mm = 32; mm >= 1; mm >>= 1) s += __shfl_xor(s, mm, 64);
                if (lane < LL) {
                    if (wid == 0) sm.ra[lane] = e / s;
                    else          sm.wmm[lane] = e / s;
                }
            }
            __syncthreads();

            // read_value + vals update (thread owns column v = tid, tid < 512)
            if (tid < VV) {
                float rv = 0.f;
                #pragma unroll 10
                for (int l = 0; l < LL; ++l) rv += sm.ra[l] * sm.vals[l * VP + tid];
                const float nv = g0 * prim[tid] + g1 * rv;
                #pragma unroll 10
                for (int l = 0; l < LL; ++l) {
                    const float w = sm.wmm[l];
                    float* cell = sm.vals + l * VP + tid;
                    *cell = fmaf(w, nv - *cell, *cell);
                }
            }

            // gh = W_hh @ h + b_hh (reads sm.h, not written above; no barrier needed)
            {
                float a0 = 0.f, a1 = 0.f;
                const unsigned* wp = wT_hh + tid;
                #pragma unroll 8
                for (int k = 0; k < HH; ++k) {
                    unsigned u = wp[k * (H3 / 2)];
                    float hk = sm.h[k];
                    a0 = fmaf(bflo(u), hk, a0);
                    a1 = fmaf(bfhi(u), hk, a1);
                }
                sm.gh[j0]     = a0 + bh2.x;
                sm.gh[j0 + 1] = a1 + bh2.y;
            }
            __syncthreads();

            // GRU pointwise
            if (tid < HH) {
                const int j = tid;
                const float r = 1.f / (1.f + expf(-(sm.gi[j] + sm.gh[j])));
                const float z = 1.f / (1.f + expf(-(sm.gi[HH + j] + sm.gh[HH + j])));
                const float n = tanhf(sm.gi[2 * HH + j] + r * sm.gh[2 * HH + j]);
                sm.h[j] = (1.f - z) * n + z * sm.h[j];
            }
            __syncthreads();
        }
    }

    // log-softmax row offsets
    for (int l = wid; l < LL; l += NT / 64) {
        const float* row = sm.vals + l * VP;
        float m = -1e30f;
        for (int v = lane; v < VV; v += 64) m = fmaxf(m, row[v]);
        #pragma unroll
        for (int mm = 32; mm >= 1; mm >>= 1) m = fmaxf(m, __shfl_xor(m, mm, 64));
        float s = 0.f;
        for (int v = lane; v < VV; v += 64) s += expf(row[v] - m);
        #pragma unroll
        for (int mm = 32; mm >= 1; mm >>= 1) s += __shfl_xor(s, mm, 64);
        if (lane == 0) sm.rowoff[l] = m + logf(s);
    }
    __syncthreads();

    // actions[b, v, l] = vals[l, v] - rowoff[l]; lanes over l (coalesced)
    {
        const int vs = wid;           // 0..8
        const int l  = lane;
        if (l < LL) {
            const float off = sm.rowoff[l];
            float* ob = out + (long)b * VV * LL + l;
            for (int v = vs; v < VV; v += NT / 64) {
                ob[(long)v * LL] = sm.vals[l * VP + v] - off;
            }
        }
    }
}

__global__ void ta_copy(const int* __restrict__ ta, float* __restrict__ out2)
{
    int idx = blockIdx.x * 256 + threadIdx.x;
    if (idx < BB * LL) {
        int b2 = idx / LL, l = idx % LL;
        out2[idx] = (float)ta[l * BB + b2];
    }
}

extern "C" void kernel_launch(void* const* d_in, const int* in_sizes, int n_in,
                              void* d_out, int out_size, void* d_ws, size_t ws_size,
                              hipStream_t stream)
{
    const int*   instr        = (const int*)  d_in[0];
    const int*   true_actions = (const int*)  d_in[1];
    const float* gate_emb     = (const float*)d_in[2];
    const float* program_emb  = (const float*)d_in[3];
    const float* primitive_emb= (const float*)d_in[4];
    const float* w_ih         = (const float*)d_in[5];
    const float* w_hh         = (const float*)d_in[6];
    const float* b_ih         = (const float*)d_in[7];
    const float* b_hh         = (const float*)d_in[8];
    const float* scratch_keys = (const float*)d_in[9];
    const float* init_value   = (const float*)d_in[10];

    unsigned short* wt = (unsigned short*)d_ws;   // needs 1.35 MB of ws
    const unsigned* wT_hh = (const unsigned*)wt;
    const unsigned* wT_ih = (const unsigned*)(wt + WT_HH_ELEMS);

    {
        int total = WT_HH_ELEMS + WT_IH_ELEMS;
        transpose_bf16<<<(total + 255) / 256, 256, 0, stream>>>(w_hh, w_ih, wt);
    }

    float* out = (float*)d_out;
    float* out_actions = out;
    float* out_ta      = out + (long)BB * VV * LL;

    symop_main<<<BB, NT, 0, stream>>>(instr, gate_emb, program_emb, primitive_emb,
                                      wT_hh, wT_ih, b_ih, b_hh,
                                      scratch_keys, init_value, out_actions);

    ta_copy<<<(BB * LL + 255) / 256, 256, 0, stream>>>(true_actions, out_ta);
}